// Round 7
// baseline (217.779 us; speedup 1.0000x reference)
//
#include <hip/hip_runtime.h>
#include <hip/hip_fp16.h>

constexpr int N  = 50000;
constexpr int E  = 1600000;
constexpr int ET = E + N;                   // with self-loops
constexpr int NF = 128;
constexpr int NB = (N + 127) / 128;         // 391 dst-buckets of 128 nodes
constexpr int EPB  = 16384;                 // edges per block (hist/scatter)
constexpr int NBLK = (ET + EPB - 1) / EPB;  // 101
constexpr int DCAP = 8192;                  // LDS edge capacity in k_csr
constexpr int SCAPW = 128;                  // per-wave edge stash in aggregate

typedef _Float16 half8 __attribute__((ext_vector_type(8)));
typedef float    f32x4 __attribute__((ext_vector_type(4)));

__global__ __launch_bounds__(1024) void k_hist(const int* __restrict__ ei, int* __restrict__ bcnt) {
    __shared__ int h[NB];
    int t = threadIdx.x;
    for (int i = t; i < NB; i += 1024) h[i] = 0;
    __syncthreads();
    int base = blockIdx.x * EPB;
#pragma unroll
    for (int k = 0; k < EPB / 1024; ++k) {
        int i = base + k * 1024 + t;
        if (i < ET) {
            int d = (i < E) ? ei[E + i] : (i - E);
            atomicAdd(&h[d >> 7], 1);
        }
    }
    __syncthreads();
    for (int i = t; i < NB; i += 1024)
        if (h[i]) atomicAdd(&bcnt[i], h[i]);
}

__global__ __launch_bounds__(512) void k_bscan(const int* __restrict__ bcnt,
                                               int* __restrict__ bbase, int* __restrict__ bcur,
                                               int* __restrict__ off) {
    __shared__ int buf[512];
    int t = threadIdx.x;
    int v = (t < NB) ? bcnt[t] : 0;
    buf[t] = v;
    __syncthreads();
    for (int o = 1; o < 512; o <<= 1) {
        int a = (t >= o) ? buf[t - o] : 0;
        __syncthreads();
        buf[t] += a;
        __syncthreads();
    }
    if (t < NB) { bbase[t] = buf[t] - v; bcur[t] = buf[t] - v; }
    if (t == 0) { bbase[NB] = ET; off[N] = ET; }
}

__global__ __launch_bounds__(1024) void k_binscatter(const int* __restrict__ ei,
                                                     int* __restrict__ bcur,
                                                     int* __restrict__ packed) {
    __shared__ int h[NB], lcur[NB], garr[NB];
    int t = threadIdx.x;
    for (int i = t; i < NB; i += 1024) h[i] = 0;
    __syncthreads();
    int base = blockIdx.x * EPB;
    int pk[EPB / 1024];
    int bk[EPB / 1024];
#pragma unroll
    for (int k = 0; k < EPB / 1024; ++k) {
        int i = base + k * 1024 + t;
        if (i < ET) {
            int s, d;
            if (i < E) { s = ei[i]; d = ei[E + i]; } else { s = i - E; d = i - E; }
            bk[k] = d >> 7;
            pk[k] = s | ((d & 127) << 16);
            atomicAdd(&h[bk[k]], 1);
        } else bk[k] = -1;
    }
    __syncthreads();
    for (int i = t; i < NB; i += 1024) {
        lcur[i] = 0;
        garr[i] = h[i] ? atomicAdd(&bcur[i], h[i]) : 0;
    }
    __syncthreads();
#pragma unroll
    for (int k = 0; k < EPB / 1024; ++k) {
        if (bk[k] >= 0) {
            int p = garr[bk[k]] + atomicAdd(&lcur[bk[k]], 1);
            packed[p] = pk[k];
        }
    }
}

__global__ __launch_bounds__(1024) void k_csr(const int* __restrict__ packed,
                                              const int* __restrict__ bbase,
                                              int* __restrict__ off,
                                              unsigned short* __restrict__ srcs) {
    int b = blockIdx.x;
    int t = threadIdx.x;
    int s0 = bbase[b], s1 = bbase[b + 1];
    int n = s1 - s0;
    __shared__ int buf[DCAP];
    __shared__ int h[128], sc[128], lcur[128];
    for (int i = t; i < n && i < DCAP; i += 1024) buf[i] = packed[s0 + i];
    if (t < 128) { h[t] = 0; lcur[t] = 0; }
    __syncthreads();
    for (int i = t; i < n; i += 1024) {
        int p = (i < DCAP) ? buf[i] : packed[s0 + i];
        atomicAdd(&h[(p >> 16) & 127], 1);
    }
    __syncthreads();
    if (t < 128) sc[t] = h[t];
    __syncthreads();
    for (int o = 1; o < 128; o <<= 1) {
        int a = (t >= o && t < 128) ? sc[t - o] : 0;
        __syncthreads();
        if (t < 128) sc[t] += a;
        __syncthreads();
    }
    if (t < 128) {
        int d = b * 128 + t;
        if (d < N) off[d] = s0 + sc[t] - h[t];
    }
    __syncthreads();
    for (int i = t; i < n; i += 1024) {
        int p = (i < DCAP) ? buf[i] : packed[s0 + i];
        int dl = (p >> 16) & 127;
        int pos = s0 + (sc[dl] - h[dl]) + atomicAdd(&lcur[dl], 1);
        srcs[pos] = (unsigned short)(p & 0xFFFF);
    }
}

// x (fp32) -> fp16, 4 elems/thread
__global__ __launch_bounds__(256) void k_cvt_x(const float* __restrict__ X, __half* __restrict__ X16) {
    int i = blockIdx.x * 256 + threadIdx.x;           // i indexes float4
    if (i >= N * NF / 4) return;
    float4 v = ((const float4*)X)[i];
    union { __half2 h[2]; uint2 u; } pk;
    pk.h[0] = __floats2half2_rn(v.x, v.y);
    pk.h[1] = __floats2half2_rn(v.z, v.w);
    ((uint2*)X16)[i] = pk.u;
}

// pack W1,W2 (fp32 [k][n]) into MFMA B-fragment order, fp16
__global__ __launch_bounds__(256) void k_packw(const float* __restrict__ W1, const float* __restrict__ W2,
                                               __half* __restrict__ P1, __half* __restrict__ P2) {
    int tid = blockIdx.x * 256 + threadIdx.x;
    if (tid >= 2 * NF * NF) return;
    int which = tid >> 14;
    int id = tid & (NF * NF - 1);
    int k = id >> 7, n = id & 127;
    const float* W = which ? W2 : W1;
    __half* P = which ? P2 : P1;
    int ks = k >> 5, r = k & 31, ct = n >> 4;
    int lane = ((r >> 3) << 4) | (n & 15);
    int j = r & 7;
    P[((ks * 8 + ct) * 64 + lane) * 8 + j] = __float2half_rn(W[k * NF + n]);
}

// H16 = fp16(A16 @ W) via mfma_f32_16x16x32_f16; alpha projections fused.
__global__ __launch_bounds__(256) void k_gemm_mfma(
    const __half* __restrict__ A16, const __half* __restrict__ Wpk,
    const float* __restrict__ asv, const float* __restrict__ adv,
    __half* __restrict__ H16, float* __restrict__ AS, float* __restrict__ AD) {
    int t = threadIdx.x;
    int wave = t >> 6, lane = t & 63;
    int base = blockIdx.x * 64 + wave * 16;

    int row_a = base + (lane & 15);
    if (row_a >= N) row_a = N - 1;
    const half8* Arow = (const half8*)(A16 + (size_t)row_a * NF);
    const half8* BP = (const half8*)Wpk;

    f32x4 acc[8] = {};
#pragma unroll
    for (int ks = 0; ks < 4; ++ks) {
        half8 a = Arow[ks * 4 + (lane >> 4)];
#pragma unroll
        for (int ct = 0; ct < 8; ++ct) {
            half8 b = BP[(ks * 8 + ct) * 64 + lane];
            acc[ct] = __builtin_amdgcn_mfma_f32_16x16x32_f16(a, b, acc[ct], 0, 0, 0);
        }
    }

    int colb = lane & 15;
    int rowq = base + (lane >> 4) * 4;
    float ps[4] = {0.f, 0.f, 0.f, 0.f};
    float pd[4] = {0.f, 0.f, 0.f, 0.f};
#pragma unroll
    for (int ct = 0; ct < 8; ++ct) {
        int col = ct * 16 + colb;
        float av = asv[col], dv = adv[col];
#pragma unroll
        for (int r = 0; r < 4; ++r) {
            float h = acc[ct][r];
            if (rowq + r < N) H16[(size_t)(rowq + r) * NF + col] = __float2half_rn(h);
            ps[r] = fmaf(h, av, ps[r]);
            pd[r] = fmaf(h, dv, pd[r]);
        }
    }
#pragma unroll
    for (int r = 0; r < 4; ++r) {
#pragma unroll
        for (int o = 1; o <= 8; o <<= 1) {
            ps[r] += __shfl_xor(ps[r], o);
            pd[r] += __shfl_xor(pd[r], o);
        }
    }
    if (colb == 0) {
#pragma unroll
        for (int r = 0; r < 4; ++r) {
            if (rowq + r < N) { AS[rowq + r] = ps[r]; AD[rowq + r] = pd[r]; }
        }
    }
}

// wave-per-dst softmax+aggregate; no max pass (exp clamp), no barriers.
// 4 dsts per 256-thread block; per-wave LDS stash of (weight, src).
template <typename OUTT, int ACT>
__global__ __launch_bounds__(256) void k_aggregate(
    const __half* __restrict__ H16, const float* __restrict__ AS, const float* __restrict__ AD,
    const int* __restrict__ off, const unsigned short* __restrict__ srcs,
    const float* __restrict__ bias, OUTT* __restrict__ OUT) {
    int wave = threadIdx.x >> 6, lane = threadIdx.x & 63;
    int d = blockIdx.x * 4 + wave;

    __shared__ float ssv[4][SCAPW];
    __shared__ unsigned short ssrc[4][SCAPW];

    int beg = off[d], deg = off[d + 1] - beg;
    float ad = AD[d];

    // pass 1: one exp per edge, stash (e, src), wave-reduce denominator
    float ls = 0.f;
    for (int i = lane; i < deg; i += 64) {
        int s = srcs[beg + i];
        float sv = AS[s] + ad;
        sv = (sv > 0.f) ? sv : 0.2f * sv;
        float e = __expf(fminf(sv, 60.f));
        if (i < SCAPW) { ssv[wave][i] = e; ssrc[wave][i] = (unsigned short)s; }
        ls += e;
    }
#pragma unroll
    for (int o = 1; o <= 32; o <<= 1) ls += __shfl_xor(ls, o);
    float inv = 1.f / (ls + 1e-16f);

    // pass 2: gather-accumulate, 4 edge slots x 16 lanes
    int tx = lane & 15, u = lane >> 4;
    float acc[8] = {0.f, 0.f, 0.f, 0.f, 0.f, 0.f, 0.f, 0.f};
    for (int j0 = 0; j0 < deg; j0 += 4) {
        int i = j0 + u;
        if (i < deg) {
            float e;
            int s;
            if (i < SCAPW) { e = ssv[wave][i]; s = ssrc[wave][i]; }
            else {                                    // cold path (deg > 128)
                s = srcs[beg + i];
                float sv = AS[s] + ad;
                sv = (sv > 0.f) ? sv : 0.2f * sv;
                e = __expf(fminf(sv, 60.f));
            }
            union { float4 f; __half2 h[4]; } v;
            v.f = *reinterpret_cast<const float4*>(H16 + (size_t)s * NF + tx * 8);
            float2 f0 = __half22float2(v.h[0]);
            float2 f1 = __half22float2(v.h[1]);
            float2 f2 = __half22float2(v.h[2]);
            float2 f3 = __half22float2(v.h[3]);
            acc[0] = fmaf(e, f0.x, acc[0]); acc[1] = fmaf(e, f0.y, acc[1]);
            acc[2] = fmaf(e, f1.x, acc[2]); acc[3] = fmaf(e, f1.y, acc[3]);
            acc[4] = fmaf(e, f2.x, acc[4]); acc[5] = fmaf(e, f2.y, acc[5]);
            acc[6] = fmaf(e, f3.x, acc[6]); acc[7] = fmaf(e, f3.y, acc[7]);
        }
    }
#pragma unroll
    for (int o = 16; o <= 32; o <<= 1) {
#pragma unroll
        for (int i = 0; i < 8; ++i) acc[i] += __shfl_xor(acc[i], o);
    }
    if (lane < 16) {
        float o8[8];
#pragma unroll
        for (int i = 0; i < 8; ++i) {
            float v = acc[i] * inv + bias[tx * 8 + i];
            o8[i] = (ACT && v < 0.f) ? 0.01f * v : v;
        }
        if constexpr (sizeof(OUTT) == 2) {
            union { __half2 h[4]; float4 f; } pk;
            pk.h[0] = __floats2half2_rn(o8[0], o8[1]);
            pk.h[1] = __floats2half2_rn(o8[2], o8[3]);
            pk.h[2] = __floats2half2_rn(o8[4], o8[5]);
            pk.h[3] = __floats2half2_rn(o8[6], o8[7]);
            ((float4*)OUT)[(size_t)d * 16 + tx] = pk.f;
        } else {
            float4 w0 = {o8[0], o8[1], o8[2], o8[3]};
            float4 w1 = {o8[4], o8[5], o8[6], o8[7]};
            ((float4*)OUT)[(size_t)d * 32 + tx * 2]     = w0;
            ((float4*)OUT)[(size_t)d * 32 + tx * 2 + 1] = w1;
        }
    }
}

extern "C" void kernel_launch(void* const* d_in, const int* in_sizes, int n_in,
                              void* d_out, int out_size, void* d_ws, size_t ws_size,
                              hipStream_t stream) {
    const float* x   = (const float*)d_in[0];
    const int*   ei  = (const int*)d_in[1];
    const float* W1  = (const float*)d_in[2];
    const float* as1 = (const float*)d_in[3];
    const float* ad1 = (const float*)d_in[4];
    const float* b1  = (const float*)d_in[5];
    const float* W2  = (const float*)d_in[6];
    const float* as2 = (const float*)d_in[7];
    const float* ad2 = (const float*)d_in[8];
    const float* b2  = (const float*)d_in[9];
    float* out = (float*)d_out;

    char* p = (char*)d_ws;
    auto alloc = [&](size_t bytes) { char* r = p; p += (bytes + 255) & ~size_t(255); return (void*)r; };
    int* bcnt  = (int*)alloc(sizeof(int) * NB);
    int* bbase = (int*)alloc(sizeof(int) * (NB + 1));
    int* bcur  = (int*)alloc(sizeof(int) * NB);
    int* off   = (int*)alloc(sizeof(int) * (N + 1));
    unsigned short* srcs = (unsigned short*)alloc(sizeof(unsigned short) * ET);
    __half* X16   = (__half*)alloc(sizeof(__half) * (size_t)N * NF);
    __half* H16   = (__half*)alloc(sizeof(__half) * (size_t)N * NF);
    __half* HMID16= (__half*)alloc(sizeof(__half) * (size_t)N * NF);
    __half* Wpk1  = (__half*)alloc(sizeof(__half) * NF * NF);
    __half* Wpk2  = (__half*)alloc(sizeof(__half) * NF * NF);
    float* AS  = (float*)alloc(sizeof(float) * N);
    float* AD  = (float*)alloc(sizeof(float) * N);
    int* packed = (int*)alloc(sizeof(int) * ET);

    // CSR build (bucketed two-level counting sort)
    hipMemsetAsync(bcnt, 0, sizeof(int) * NB, stream);
    k_hist<<<NBLK, 1024, 0, stream>>>(ei, bcnt);
    k_bscan<<<1, 512, 0, stream>>>(bcnt, bbase, bcur, off);
    k_binscatter<<<NBLK, 1024, 0, stream>>>(ei, bcur, packed);
    k_csr<<<NB, 1024, 0, stream>>>(packed, bbase, off, srcs);

    // fp16 conversions / weight packing
    k_cvt_x<<<(N * NF / 4 + 255) / 256, 256, 0, stream>>>(x, X16);
    k_packw<<<(2 * NF * NF + 255) / 256, 256, 0, stream>>>(W1, W2, Wpk1, Wpk2);

    // layer 1
    k_gemm_mfma<<<(N + 63) / 64, 256, 0, stream>>>(X16, Wpk1, as1, ad1, H16, AS, AD);
    k_aggregate<__half, 1><<<N / 4, 256, 0, stream>>>(H16, AS, AD, off, srcs, b1, HMID16);
    // layer 2
    k_gemm_mfma<<<(N + 63) / 64, 256, 0, stream>>>(HMID16, Wpk2, as2, ad2, H16, AS, AD);
    k_aggregate<float, 0><<<N / 4, 256, 0, stream>>>(H16, AS, AD, off, srcs, b2, out);
}

// Round 8
// 186.116 us; speedup vs baseline: 1.1701x; 1.1701x over previous
//
#include <hip/hip_runtime.h>
#include <hip/hip_fp16.h>

constexpr int N  = 50000;
constexpr int E  = 1600000;
constexpr int ET = E + N;                   // with self-loops
constexpr int NF = 128;
constexpr int NB = (N + 127) / 128;         // 391 dst-buckets of 128 nodes
constexpr int CAP = 8192;                   // fixed slots per bucket (mean 4224, sigma 65)
constexpr int EPB  = 8192;                  // edges per block (binscatter)
constexpr int NBLK = (ET + EPB - 1) / EPB;  // 202
constexpr int SCAPW = 128;                  // per-wave edge stash in aggregate

typedef _Float16 half8 __attribute__((ext_vector_type(8)));
typedef float    f32x4 __attribute__((ext_vector_type(4)));

__global__ __launch_bounds__(512) void k_initcur(int* __restrict__ bcur) {
    int i = threadIdx.x;
    if (i < NB) bcur[i] = i * CAP;
}

// bucket-binned scatter with fixed-capacity buckets: per-block LDS hist,
// one contiguous global run per (block,bucket), append packed (src | dlow<<16)
__global__ __launch_bounds__(1024) void k_binscatter(const int* __restrict__ ei,
                                                     int* __restrict__ bcur,
                                                     int* __restrict__ packed) {
    __shared__ int h[NB], lcur[NB], garr[NB];
    int t = threadIdx.x;
    for (int i = t; i < NB; i += 1024) h[i] = 0;
    __syncthreads();
    int base = blockIdx.x * EPB;
    int pk[EPB / 1024];
    int bk[EPB / 1024];
#pragma unroll
    for (int k = 0; k < EPB / 1024; ++k) {
        int i = base + k * 1024 + t;
        if (i < ET) {
            int s, d;
            if (i < E) { s = ei[i]; d = ei[E + i]; } else { s = i - E; d = i - E; }
            bk[k] = d >> 7;
            pk[k] = s | ((d & 127) << 16);
            atomicAdd(&h[bk[k]], 1);
        } else bk[k] = -1;
    }
    __syncthreads();
    for (int i = t; i < NB; i += 1024) {
        lcur[i] = 0;
        garr[i] = h[i] ? atomicAdd(&bcur[i], h[i]) : 0;
    }
    __syncthreads();
#pragma unroll
    for (int k = 0; k < EPB / 1024; ++k) {
        if (bk[k] >= 0) {
            int p = garr[bk[k]] + atomicAdd(&lcur[bk[k]], 1);
            packed[p] = pk[k];
        }
    }
}

// one block per bucket: local counting sort over its 128 dsts in LDS.
// bucket count read from final cursor; output region [b*CAP, b*CAP+n).
__global__ __launch_bounds__(1024) void k_csr(const int* __restrict__ packed,
                                              const int* __restrict__ bcur,
                                              int* __restrict__ offB, int* __restrict__ offE,
                                              unsigned short* __restrict__ srcs) {
    int b = blockIdx.x;
    int t = threadIdx.x;
    int s0 = b * CAP;
    int n = bcur[b] - s0;
    __shared__ int buf[CAP];
    __shared__ int h[128], sc[128], lcur[128];
    for (int i = t; i < n; i += 1024) buf[i] = packed[s0 + i];
    if (t < 128) { h[t] = 0; lcur[t] = 0; }
    __syncthreads();
    for (int i = t; i < n; i += 1024)
        atomicAdd(&h[(buf[i] >> 16) & 127], 1);
    __syncthreads();
    if (t < 128) sc[t] = h[t];
    __syncthreads();
    for (int o = 1; o < 128; o <<= 1) {
        int a = (t >= o && t < 128) ? sc[t - o] : 0;
        __syncthreads();
        if (t < 128) sc[t] += a;
        __syncthreads();
    }
    if (t < 128) {
        int d = b * 128 + t;
        if (d < N) {
            offB[d] = s0 + sc[t] - h[t];
            offE[d] = s0 + sc[t];
        }
    }
    __syncthreads();
    for (int i = t; i < n; i += 1024) {
        int p = buf[i];
        int dl = (p >> 16) & 127;
        int pos = s0 + (sc[dl] - h[dl]) + atomicAdd(&lcur[dl], 1);
        srcs[pos] = (unsigned short)(p & 0xFFFF);
    }
}

// x (fp32) -> fp16, 4 elems/thread
__global__ __launch_bounds__(256) void k_cvt_x(const float* __restrict__ X, __half* __restrict__ X16) {
    int i = blockIdx.x * 256 + threadIdx.x;           // i indexes float4
    if (i >= N * NF / 4) return;
    float4 v = ((const float4*)X)[i];
    union { __half2 h[2]; uint2 u; } pk;
    pk.h[0] = __floats2half2_rn(v.x, v.y);
    pk.h[1] = __floats2half2_rn(v.z, v.w);
    ((uint2*)X16)[i] = pk.u;
}

// pack W1,W2 (fp32 [k][n]) into MFMA B-fragment order, fp16
__global__ __launch_bounds__(256) void k_packw(const float* __restrict__ W1, const float* __restrict__ W2,
                                               __half* __restrict__ P1, __half* __restrict__ P2) {
    int tid = blockIdx.x * 256 + threadIdx.x;
    if (tid >= 2 * NF * NF) return;
    int which = tid >> 14;
    int id = tid & (NF * NF - 1);
    int k = id >> 7, n = id & 127;
    const float* W = which ? W2 : W1;
    __half* P = which ? P2 : P1;
    int ks = k >> 5, r = k & 31, ct = n >> 4;
    int lane = ((r >> 3) << 4) | (n & 15);
    int j = r & 7;
    P[((ks * 8 + ct) * 64 + lane) * 8 + j] = __float2half_rn(W[k * NF + n]);
}

// H16 = fp16(A16 @ W) via mfma_f32_16x16x32_f16; alpha projections fused.
__global__ __launch_bounds__(256) void k_gemm_mfma(
    const __half* __restrict__ A16, const __half* __restrict__ Wpk,
    const float* __restrict__ asv, const float* __restrict__ adv,
    __half* __restrict__ H16, float* __restrict__ AS, float* __restrict__ AD) {
    int t = threadIdx.x;
    int wave = t >> 6, lane = t & 63;
    int base = blockIdx.x * 64 + wave * 16;

    int row_a = base + (lane & 15);
    if (row_a >= N) row_a = N - 1;
    const half8* Arow = (const half8*)(A16 + (size_t)row_a * NF);
    const half8* BP = (const half8*)Wpk;

    f32x4 acc[8] = {};
#pragma unroll
    for (int ks = 0; ks < 4; ++ks) {
        half8 a = Arow[ks * 4 + (lane >> 4)];
#pragma unroll
        for (int ct = 0; ct < 8; ++ct) {
            half8 b = BP[(ks * 8 + ct) * 64 + lane];
            acc[ct] = __builtin_amdgcn_mfma_f32_16x16x32_f16(a, b, acc[ct], 0, 0, 0);
        }
    }

    int colb = lane & 15;
    int rowq = base + (lane >> 4) * 4;
    float ps[4] = {0.f, 0.f, 0.f, 0.f};
    float pd[4] = {0.f, 0.f, 0.f, 0.f};
#pragma unroll
    for (int ct = 0; ct < 8; ++ct) {
        int col = ct * 16 + colb;
        float av = asv[col], dv = adv[col];
#pragma unroll
        for (int r = 0; r < 4; ++r) {
            float h = acc[ct][r];
            if (rowq + r < N) H16[(size_t)(rowq + r) * NF + col] = __float2half_rn(h);
            ps[r] = fmaf(h, av, ps[r]);
            pd[r] = fmaf(h, dv, pd[r]);
        }
    }
#pragma unroll
    for (int r = 0; r < 4; ++r) {
#pragma unroll
        for (int o = 1; o <= 8; o <<= 1) {
            ps[r] += __shfl_xor(ps[r], o);
            pd[r] += __shfl_xor(pd[r], o);
        }
    }
    if (colb == 0) {
#pragma unroll
        for (int r = 0; r < 4; ++r) {
            if (rowq + r < N) { AS[rowq + r] = ps[r]; AD[rowq + r] = pd[r]; }
        }
    }
}

// wave-per-dst softmax+aggregate; no max pass (exp clamp), no barriers.
// 4 dsts per 256-thread block; per-wave LDS stash; 2x-unrolled gather.
template <typename OUTT, int ACT>
__global__ __launch_bounds__(256) void k_aggregate(
    const __half* __restrict__ H16, const float* __restrict__ AS, const float* __restrict__ AD,
    const int* __restrict__ offB, const int* __restrict__ offE,
    const unsigned short* __restrict__ srcs,
    const float* __restrict__ bias, OUTT* __restrict__ OUT) {
    int wave = threadIdx.x >> 6, lane = threadIdx.x & 63;
    int d = blockIdx.x * 4 + wave;

    __shared__ float ssv[4][SCAPW];
    __shared__ unsigned short ssrc[4][SCAPW];

    int beg = offB[d], deg = offE[d] - beg;
    float ad = AD[d];

    // pass 1: one exp per edge, stash (e, src), wave-reduce denominator
    float ls = 0.f;
    for (int i = lane; i < deg; i += 64) {
        int s = srcs[beg + i];
        float sv = AS[s] + ad;
        sv = (sv > 0.f) ? sv : 0.2f * sv;
        float e = __expf(fminf(sv, 60.f));
        if (i < SCAPW) { ssv[wave][i] = e; ssrc[wave][i] = (unsigned short)s; }
        ls += e;
    }
#pragma unroll
    for (int o = 1; o <= 32; o <<= 1) ls += __shfl_xor(ls, o);
    float inv = 1.f / (ls + 1e-16f);

    // pass 2: gather-accumulate, 2x unrolled (8 edges in flight per wave)
    int tx = lane & 15, u = lane >> 4;
    float acc[8] = {0.f, 0.f, 0.f, 0.f, 0.f, 0.f, 0.f, 0.f};
    for (int j0 = 0; j0 < deg; j0 += 8) {
        int i0 = j0 + u, i1 = j0 + 4 + u;
        float e0 = 0.f, e1 = 0.f;
        int s0 = 0, s1 = 0;
        bool v0 = i0 < deg, v1 = i1 < deg;
        if (v0) {
            if (i0 < SCAPW) { e0 = ssv[wave][i0]; s0 = ssrc[wave][i0]; }
            else {
                s0 = srcs[beg + i0];
                float sv = AS[s0] + ad;
                sv = (sv > 0.f) ? sv : 0.2f * sv;
                e0 = __expf(fminf(sv, 60.f));
            }
        }
        if (v1) {
            if (i1 < SCAPW) { e1 = ssv[wave][i1]; s1 = ssrc[wave][i1]; }
            else {
                s1 = srcs[beg + i1];
                float sv = AS[s1] + ad;
                sv = (sv > 0.f) ? sv : 0.2f * sv;
                e1 = __expf(fminf(sv, 60.f));
            }
        }
        union { float4 f; __half2 h[4]; } va, vb;
        if (v0) va.f = *reinterpret_cast<const float4*>(H16 + (size_t)s0 * NF + tx * 8);
        if (v1) vb.f = *reinterpret_cast<const float4*>(H16 + (size_t)s1 * NF + tx * 8);
        if (v0) {
            float2 f0 = __half22float2(va.h[0]);
            float2 f1 = __half22float2(va.h[1]);
            float2 f2 = __half22float2(va.h[2]);
            float2 f3 = __half22float2(va.h[3]);
            acc[0] = fmaf(e0, f0.x, acc[0]); acc[1] = fmaf(e0, f0.y, acc[1]);
            acc[2] = fmaf(e0, f1.x, acc[2]); acc[3] = fmaf(e0, f1.y, acc[3]);
            acc[4] = fmaf(e0, f2.x, acc[4]); acc[5] = fmaf(e0, f2.y, acc[5]);
            acc[6] = fmaf(e0, f3.x, acc[6]); acc[7] = fmaf(e0, f3.y, acc[7]);
        }
        if (v1) {
            float2 f0 = __half22float2(vb.h[0]);
            float2 f1 = __half22float2(vb.h[1]);
            float2 f2 = __half22float2(vb.h[2]);
            float2 f3 = __half22float2(vb.h[3]);
            acc[0] = fmaf(e1, f0.x, acc[0]); acc[1] = fmaf(e1, f0.y, acc[1]);
            acc[2] = fmaf(e1, f1.x, acc[2]); acc[3] = fmaf(e1, f1.y, acc[3]);
            acc[4] = fmaf(e1, f2.x, acc[4]); acc[5] = fmaf(e1, f2.y, acc[5]);
            acc[6] = fmaf(e1, f3.x, acc[6]); acc[7] = fmaf(e1, f3.y, acc[7]);
        }
    }
#pragma unroll
    for (int o = 16; o <= 32; o <<= 1) {
#pragma unroll
        for (int i = 0; i < 8; ++i) acc[i] += __shfl_xor(acc[i], o);
    }
    if (lane < 16) {
        float o8[8];
#pragma unroll
        for (int i = 0; i < 8; ++i) {
            float v = acc[i] * inv + bias[tx * 8 + i];
            o8[i] = (ACT && v < 0.f) ? 0.01f * v : v;
        }
        if constexpr (sizeof(OUTT) == 2) {
            union { __half2 h[4]; float4 f; } pk;
            pk.h[0] = __floats2half2_rn(o8[0], o8[1]);
            pk.h[1] = __floats2half2_rn(o8[2], o8[3]);
            pk.h[2] = __floats2half2_rn(o8[4], o8[5]);
            pk.h[3] = __floats2half2_rn(o8[6], o8[7]);
            ((float4*)OUT)[(size_t)d * 16 + tx] = pk.f;
        } else {
            float4 w0 = {o8[0], o8[1], o8[2], o8[3]};
            float4 w1 = {o8[4], o8[5], o8[6], o8[7]};
            ((float4*)OUT)[(size_t)d * 32 + tx * 2]     = w0;
            ((float4*)OUT)[(size_t)d * 32 + tx * 2 + 1] = w1;
        }
    }
}

extern "C" void kernel_launch(void* const* d_in, const int* in_sizes, int n_in,
                              void* d_out, int out_size, void* d_ws, size_t ws_size,
                              hipStream_t stream) {
    const float* x   = (const float*)d_in[0];
    const int*   ei  = (const int*)d_in[1];
    const float* W1  = (const float*)d_in[2];
    const float* as1 = (const float*)d_in[3];
    const float* ad1 = (const float*)d_in[4];
    const float* b1  = (const float*)d_in[5];
    const float* W2  = (const float*)d_in[6];
    const float* as2 = (const float*)d_in[7];
    const float* ad2 = (const float*)d_in[8];
    const float* b2  = (const float*)d_in[9];
    float* out = (float*)d_out;

    char* p = (char*)d_ws;
    auto alloc = [&](size_t bytes) { char* r = p; p += (bytes + 255) & ~size_t(255); return (void*)r; };
    int* bcur  = (int*)alloc(sizeof(int) * NB);
    int* offB  = (int*)alloc(sizeof(int) * N);
    int* offE  = (int*)alloc(sizeof(int) * N);
    unsigned short* srcs = (unsigned short*)alloc(sizeof(unsigned short) * (size_t)NB * CAP);
    __half* X16   = (__half*)alloc(sizeof(__half) * (size_t)N * NF);
    __half* H16   = (__half*)alloc(sizeof(__half) * (size_t)N * NF);
    __half* HMID16= (__half*)alloc(sizeof(__half) * (size_t)N * NF);
    __half* Wpk1  = (__half*)alloc(sizeof(__half) * NF * NF);
    __half* Wpk2  = (__half*)alloc(sizeof(__half) * NF * NF);
    float* AS  = (float*)alloc(sizeof(float) * N);
    float* AD  = (float*)alloc(sizeof(float) * N);
    int* packed = (int*)alloc(sizeof(int) * (size_t)NB * CAP);

    // CSR build: fixed-capacity bucket binning (no hist, no scan)
    k_initcur<<<1, 512, 0, stream>>>(bcur);
    k_binscatter<<<NBLK, 1024, 0, stream>>>(ei, bcur, packed);
    k_csr<<<NB, 1024, 0, stream>>>(packed, bcur, offB, offE, srcs);

    // fp16 conversions / weight packing
    k_cvt_x<<<(N * NF / 4 + 255) / 256, 256, 0, stream>>>(x, X16);
    k_packw<<<(2 * NF * NF + 255) / 256, 256, 0, stream>>>(W1, W2, Wpk1, Wpk2);

    // layer 1
    k_gemm_mfma<<<(N + 63) / 64, 256, 0, stream>>>(X16, Wpk1, as1, ad1, H16, AS, AD);
    k_aggregate<__half, 1><<<N / 4, 256, 0, stream>>>(H16, AS, AD, offB, offE, srcs, b1, HMID16);
    // layer 2
    k_gemm_mfma<<<(N + 63) / 64, 256, 0, stream>>>(HMID16, Wpk2, as2, ad2, H16, AS, AD);
    k_aggregate<float, 0><<<N / 4, 256, 0, stream>>>(H16, AS, AD, offB, offE, srcs, b2, out);
}

// Round 9
// 185.930 us; speedup vs baseline: 1.1713x; 1.0010x over previous
//
#include <hip/hip_runtime.h>
#include <hip/hip_fp16.h>

constexpr int N  = 50000;
constexpr int E  = 1600000;
constexpr int ET = E + N;                   // with self-loops
constexpr int NF = 128;
constexpr int BSH = 64;                     // dsts per bucket
constexpr int NB = (N + BSH - 1) / BSH;     // 782 buckets
constexpr int CAP = 4096;                   // slots per bucket (mean 2110, sigma 46)
constexpr int EPB  = 2048;                  // edges per block (binscatter)
constexpr int NBLK = (ET + EPB - 1) / EPB;  // 806
constexpr int SCAPW = 128;                  // per-wave edge stash in aggregate

typedef _Float16 half8 __attribute__((ext_vector_type(8)));
typedef float    f32x4 __attribute__((ext_vector_type(4)));

__global__ __launch_bounds__(1024) void k_initcur(int* __restrict__ bcur) {
    int i = threadIdx.x;
    if (i < NB) bcur[i] = i * CAP;
}

// bucket-binned scatter, fixed-capacity buckets: per-block LDS hist over 782
// buckets, one contiguous global run per (block,bucket), append (src | dlow<<16)
__global__ __launch_bounds__(1024) void k_binscatter(const int* __restrict__ ei,
                                                     int* __restrict__ bcur,
                                                     int* __restrict__ packed) {
    __shared__ int h[NB], lcur[NB], garr[NB];
    int t = threadIdx.x;
    for (int i = t; i < NB; i += 1024) h[i] = 0;
    __syncthreads();
    int base = blockIdx.x * EPB;
    int pk[EPB / 1024];
    int bk[EPB / 1024];
#pragma unroll
    for (int k = 0; k < EPB / 1024; ++k) {
        int i = base + k * 1024 + t;
        if (i < ET) {
            int s, d;
            if (i < E) { s = ei[i]; d = ei[E + i]; } else { s = i - E; d = i - E; }
            bk[k] = d / BSH;
            pk[k] = s | ((d & (BSH - 1)) << 16);
            atomicAdd(&h[bk[k]], 1);
        } else bk[k] = -1;
    }
    __syncthreads();
    for (int i = t; i < NB; i += 1024) {
        lcur[i] = 0;
        garr[i] = h[i] ? atomicAdd(&bcur[i], h[i]) : 0;
    }
    __syncthreads();
#pragma unroll
    for (int k = 0; k < EPB / 1024; ++k) {
        if (bk[k] >= 0) {
            int p = garr[bk[k]] + atomicAdd(&lcur[bk[k]], 1);
            packed[p] = pk[k];
        }
    }
}

// one block per bucket: counting sort over 64 dsts in LDS; single-wave shfl scan
__global__ __launch_bounds__(512) void k_csr(const int* __restrict__ packed,
                                             const int* __restrict__ bcur,
                                             int* __restrict__ offB, int* __restrict__ offE,
                                             unsigned short* __restrict__ srcs) {
    int b = blockIdx.x;
    int t = threadIdx.x;
    int s0 = b * CAP;
    int n = bcur[b] - s0;
    __shared__ int buf[CAP];
    __shared__ int bas[BSH], lcur[BSH];
    for (int i = t; i < n; i += 512) buf[i] = packed[s0 + i];
    __shared__ int h[BSH];
    if (t < BSH) { h[t] = 0; lcur[t] = 0; }
    __syncthreads();
    for (int i = t; i < n; i += 512)
        atomicAdd(&h[(buf[i] >> 16) & (BSH - 1)], 1);
    __syncthreads();
    if (t < BSH) {                          // exactly one wave does the 64-bin scan
        int v = h[t], x = v;
#pragma unroll
        for (int o = 1; o < 64; o <<= 1) {
            int y = __shfl_up(x, o);
            if (t >= o) x += y;
        }
        bas[t] = s0 + x - v;
        int d = b * BSH + t;
        if (d < N) { offB[d] = s0 + x - v; offE[d] = s0 + x; }
    }
    __syncthreads();
    for (int i = t; i < n; i += 512) {
        int p = buf[i];
        int dl = (p >> 16) & (BSH - 1);
        int pos = bas[dl] + atomicAdd(&lcur[dl], 1);
        srcs[pos] = (unsigned short)(p & 0xFFFF);
    }
}

// pack W1,W2 (fp32 [k][n]) into MFMA B-fragment order, fp16
__global__ __launch_bounds__(256) void k_packw(const float* __restrict__ W1, const float* __restrict__ W2,
                                               __half* __restrict__ P1, __half* __restrict__ P2) {
    int tid = blockIdx.x * 256 + threadIdx.x;
    if (tid >= 2 * NF * NF) return;
    int which = tid >> 14;
    int id = tid & (NF * NF - 1);
    int k = id >> 7, n = id & 127;
    const float* W = which ? W2 : W1;
    __half* P = which ? P2 : P1;
    int ks = k >> 5, r = k & 31, ct = n >> 4;
    int lane = ((r >> 3) << 4) | (n & 15);
    int j = r & 7;
    P[((ks * 8 + ct) * 64 + lane) * 8 + j] = __float2half_rn(W[k * NF + n]);
}

// H16 = fp16(A @ W) via mfma_f32_16x16x32_f16; A is fp32 (layer1) or fp16 (layer2).
// Alpha projections fused from fp32 accumulators.
template <typename AT>
__global__ __launch_bounds__(256) void k_gemm_mfma(
    const AT* __restrict__ A, const __half* __restrict__ Wpk,
    const float* __restrict__ asv, const float* __restrict__ adv,
    __half* __restrict__ H16, float* __restrict__ AS, float* __restrict__ AD) {
    int t = threadIdx.x;
    int wave = t >> 6, lane = t & 63;
    int base = blockIdx.x * 64 + wave * 16;

    int row_a = base + (lane & 15);
    if (row_a >= N) row_a = N - 1;
    const AT* Arow = A + (size_t)row_a * NF;
    const half8* BP = (const half8*)Wpk;

    f32x4 acc[8] = {};
#pragma unroll
    for (int ks = 0; ks < 4; ++ks) {
        int eo = (ks * 4 + (lane >> 4)) * 8;
        half8 a;
        if constexpr (sizeof(AT) == 4) {
            float4 u = *(const float4*)(Arow + eo);
            float4 v = *(const float4*)(Arow + eo + 4);
            a[0] = (_Float16)u.x; a[1] = (_Float16)u.y; a[2] = (_Float16)u.z; a[3] = (_Float16)u.w;
            a[4] = (_Float16)v.x; a[5] = (_Float16)v.y; a[6] = (_Float16)v.z; a[7] = (_Float16)v.w;
        } else {
            a = ((const half8*)Arow)[ks * 4 + (lane >> 4)];
        }
#pragma unroll
        for (int ct = 0; ct < 8; ++ct) {
            half8 b = BP[(ks * 8 + ct) * 64 + lane];
            acc[ct] = __builtin_amdgcn_mfma_f32_16x16x32_f16(a, b, acc[ct], 0, 0, 0);
        }
    }

    int colb = lane & 15;
    int rowq = base + (lane >> 4) * 4;
    float ps[4] = {0.f, 0.f, 0.f, 0.f};
    float pd[4] = {0.f, 0.f, 0.f, 0.f};
#pragma unroll
    for (int ct = 0; ct < 8; ++ct) {
        int col = ct * 16 + colb;
        float av = asv[col], dv = adv[col];
#pragma unroll
        for (int r = 0; r < 4; ++r) {
            float h = acc[ct][r];
            if (rowq + r < N) H16[(size_t)(rowq + r) * NF + col] = __float2half_rn(h);
            ps[r] = fmaf(h, av, ps[r]);
            pd[r] = fmaf(h, dv, pd[r]);
        }
    }
#pragma unroll
    for (int r = 0; r < 4; ++r) {
#pragma unroll
        for (int o = 1; o <= 8; o <<= 1) {
            ps[r] += __shfl_xor(ps[r], o);
            pd[r] += __shfl_xor(pd[r], o);
        }
    }
    if (colb == 0) {
#pragma unroll
        for (int r = 0; r < 4; ++r) {
            if (rowq + r < N) { AS[rowq + r] = ps[r]; AD[rowq + r] = pd[r]; }
        }
    }
}

// wave-per-dst softmax+aggregate; no max pass (exp clamp), no barriers.
// 4 dsts per 256-thread block; per-wave LDS stash; 2x-unrolled gather.
template <typename OUTT, int ACT>
__global__ __launch_bounds__(256) void k_aggregate(
    const __half* __restrict__ H16, const float* __restrict__ AS, const float* __restrict__ AD,
    const int* __restrict__ offB, const int* __restrict__ offE,
    const unsigned short* __restrict__ srcs,
    const float* __restrict__ bias, OUTT* __restrict__ OUT) {
    int wave = threadIdx.x >> 6, lane = threadIdx.x & 63;
    int d = blockIdx.x * 4 + wave;

    __shared__ float ssv[4][SCAPW];
    __shared__ unsigned short ssrc[4][SCAPW];

    int beg = offB[d], deg = offE[d] - beg;
    float ad = AD[d];

    // pass 1: one exp per edge, stash (e, src), wave-reduce denominator
    float ls = 0.f;
    for (int i = lane; i < deg; i += 64) {
        int s = srcs[beg + i];
        float sv = AS[s] + ad;
        sv = (sv > 0.f) ? sv : 0.2f * sv;
        float e = __expf(fminf(sv, 60.f));
        if (i < SCAPW) { ssv[wave][i] = e; ssrc[wave][i] = (unsigned short)s; }
        ls += e;
    }
#pragma unroll
    for (int o = 1; o <= 32; o <<= 1) ls += __shfl_xor(ls, o);
    float inv = 1.f / (ls + 1e-16f);

    // pass 2: gather-accumulate, 2x unrolled (8 edges in flight per wave)
    int tx = lane & 15, u = lane >> 4;
    float acc[8] = {0.f, 0.f, 0.f, 0.f, 0.f, 0.f, 0.f, 0.f};
    for (int j0 = 0; j0 < deg; j0 += 8) {
        int i0 = j0 + u, i1 = j0 + 4 + u;
        float e0 = 0.f, e1 = 0.f;
        int s0 = 0, s1 = 0;
        bool v0 = i0 < deg, v1 = i1 < deg;
        if (v0) {
            if (i0 < SCAPW) { e0 = ssv[wave][i0]; s0 = ssrc[wave][i0]; }
            else {
                s0 = srcs[beg + i0];
                float sv = AS[s0] + ad;
                sv = (sv > 0.f) ? sv : 0.2f * sv;
                e0 = __expf(fminf(sv, 60.f));
            }
        }
        if (v1) {
            if (i1 < SCAPW) { e1 = ssv[wave][i1]; s1 = ssrc[wave][i1]; }
            else {
                s1 = srcs[beg + i1];
                float sv = AS[s1] + ad;
                sv = (sv > 0.f) ? sv : 0.2f * sv;
                e1 = __expf(fminf(sv, 60.f));
            }
        }
        union { float4 f; __half2 h[4]; } va, vb;
        if (v0) va.f = *reinterpret_cast<const float4*>(H16 + (size_t)s0 * NF + tx * 8);
        if (v1) vb.f = *reinterpret_cast<const float4*>(H16 + (size_t)s1 * NF + tx * 8);
        if (v0) {
            float2 f0 = __half22float2(va.h[0]);
            float2 f1 = __half22float2(va.h[1]);
            float2 f2 = __half22float2(va.h[2]);
            float2 f3 = __half22float2(va.h[3]);
            acc[0] = fmaf(e0, f0.x, acc[0]); acc[1] = fmaf(e0, f0.y, acc[1]);
            acc[2] = fmaf(e0, f1.x, acc[2]); acc[3] = fmaf(e0, f1.y, acc[3]);
            acc[4] = fmaf(e0, f2.x, acc[4]); acc[5] = fmaf(e0, f2.y, acc[5]);
            acc[6] = fmaf(e0, f3.x, acc[6]); acc[7] = fmaf(e0, f3.y, acc[7]);
        }
        if (v1) {
            float2 f0 = __half22float2(vb.h[0]);
            float2 f1 = __half22float2(vb.h[1]);
            float2 f2 = __half22float2(vb.h[2]);
            float2 f3 = __half22float2(vb.h[3]);
            acc[0] = fmaf(e1, f0.x, acc[0]); acc[1] = fmaf(e1, f0.y, acc[1]);
            acc[2] = fmaf(e1, f1.x, acc[2]); acc[3] = fmaf(e1, f1.y, acc[3]);
            acc[4] = fmaf(e1, f2.x, acc[4]); acc[5] = fmaf(e1, f2.y, acc[5]);
            acc[6] = fmaf(e1, f3.x, acc[6]); acc[7] = fmaf(e1, f3.y, acc[7]);
        }
    }
#pragma unroll
    for (int o = 16; o <= 32; o <<= 1) {
#pragma unroll
        for (int i = 0; i < 8; ++i) acc[i] += __shfl_xor(acc[i], o);
    }
    if (lane < 16) {
        float o8[8];
#pragma unroll
        for (int i = 0; i < 8; ++i) {
            float v = acc[i] * inv + bias[tx * 8 + i];
            o8[i] = (ACT && v < 0.f) ? 0.01f * v : v;
        }
        if constexpr (sizeof(OUTT) == 2) {
            union { __half2 h[4]; float4 f; } pk;
            pk.h[0] = __floats2half2_rn(o8[0], o8[1]);
            pk.h[1] = __floats2half2_rn(o8[2], o8[3]);
            pk.h[2] = __floats2half2_rn(o8[4], o8[5]);
            pk.h[3] = __floats2half2_rn(o8[6], o8[7]);
            ((float4*)OUT)[(size_t)d * 16 + tx] = pk.f;
        } else {
            float4 w0 = {o8[0], o8[1], o8[2], o8[3]};
            float4 w1 = {o8[4], o8[5], o8[6], o8[7]};
            ((float4*)OUT)[(size_t)d * 32 + tx * 2]     = w0;
            ((float4*)OUT)[(size_t)d * 32 + tx * 2 + 1] = w1;
        }
    }
}

extern "C" void kernel_launch(void* const* d_in, const int* in_sizes, int n_in,
                              void* d_out, int out_size, void* d_ws, size_t ws_size,
                              hipStream_t stream) {
    const float* x   = (const float*)d_in[0];
    const int*   ei  = (const int*)d_in[1];
    const float* W1  = (const float*)d_in[2];
    const float* as1 = (const float*)d_in[3];
    const float* ad1 = (const float*)d_in[4];
    const float* b1  = (const float*)d_in[5];
    const float* W2  = (const float*)d_in[6];
    const float* as2 = (const float*)d_in[7];
    const float* ad2 = (const float*)d_in[8];
    const float* b2  = (const float*)d_in[9];
    float* out = (float*)d_out;

    char* p = (char*)d_ws;
    auto alloc = [&](size_t bytes) { char* r = p; p += (bytes + 255) & ~size_t(255); return (void*)r; };
    int* bcur  = (int*)alloc(sizeof(int) * NB);
    int* offB  = (int*)alloc(sizeof(int) * N);
    int* offE  = (int*)alloc(sizeof(int) * N);
    unsigned short* srcs = (unsigned short*)alloc(sizeof(unsigned short) * (size_t)NB * CAP);
    __half* H16   = (__half*)alloc(sizeof(__half) * (size_t)N * NF);
    __half* HMID16= (__half*)alloc(sizeof(__half) * (size_t)N * NF);
    __half* Wpk1  = (__half*)alloc(sizeof(__half) * NF * NF);
    __half* Wpk2  = (__half*)alloc(sizeof(__half) * NF * NF);
    float* AS  = (float*)alloc(sizeof(float) * N);
    float* AD  = (float*)alloc(sizeof(float) * N);
    int* packed = (int*)alloc(sizeof(int) * (size_t)NB * CAP);

    // CSR build: fixed-capacity bucket binning (no hist pass, no global scan)
    k_initcur<<<1, 1024, 0, stream>>>(bcur);
    k_binscatter<<<NBLK, 1024, 0, stream>>>(ei, bcur, packed);
    k_csr<<<NB, 512, 0, stream>>>(packed, bcur, offB, offE, srcs);

    // weight packing (fp32 -> fp16 fragment order)
    k_packw<<<(2 * NF * NF + 255) / 256, 256, 0, stream>>>(W1, W2, Wpk1, Wpk2);

    // layer 1 (A = fp32 x, converted in-register)
    k_gemm_mfma<float><<<(N + 63) / 64, 256, 0, stream>>>(x, Wpk1, as1, ad1, H16, AS, AD);
    k_aggregate<__half, 1><<<N / 4, 256, 0, stream>>>(H16, AS, AD, offB, offE, srcs, b1, HMID16);
    // layer 2 (A = fp16 HMID16)
    k_gemm_mfma<__half><<<(N + 63) / 64, 256, 0, stream>>>(HMID16, Wpk2, as2, ad2, H16, AS, AD);
    k_aggregate<float, 0><<<N / 4, 256, 0, stream>>>(H16, AS, AD, offB, offE, srcs, b2, out);
}

// Round 10
// 178.727 us; speedup vs baseline: 1.2185x; 1.0403x over previous
//
#include <hip/hip_runtime.h>
#include <hip/hip_fp16.h>

constexpr int N  = 50000;
constexpr int E  = 1600000;
constexpr int ET = E + N;                   // with self-loops
constexpr int NF = 128;
constexpr int BSH = 128;                    // dsts per bucket
constexpr int NB = (N + BSH - 1) / BSH;     // 391 buckets
constexpr int CAP = 8192;                   // slots per bucket (mean 4224, sigma 65)
constexpr int EPB  = 8192;                  // edges per block (binscatter)
constexpr int NBLK = (ET + EPB - 1) / EPB;  // 202
constexpr int SCAPW = 128;                  // per-wave edge stash in aggregate

typedef _Float16 half8 __attribute__((ext_vector_type(8)));
typedef float    f32x4 __attribute__((ext_vector_type(4)));

// fused: init bucket cursors + pack W1,W2 into MFMA B-fragment order (fp16)
__global__ __launch_bounds__(256) void k_init_packw(
    int* __restrict__ bcur,
    const float* __restrict__ W1, const float* __restrict__ W2,
    __half* __restrict__ P1, __half* __restrict__ P2) {
    int tid = blockIdx.x * 256 + threadIdx.x;
    if (tid < NB) bcur[tid] = tid * CAP;
    if (tid >= 2 * NF * NF) return;
    int which = tid >> 14;
    int id = tid & (NF * NF - 1);
    int k = id >> 7, n = id & 127;
    const float* W = which ? W2 : W1;
    __half* P = which ? P2 : P1;
    int ks = k >> 5, r = k & 31, ct = n >> 4;
    int lane = ((r >> 3) << 4) | (n & 15);
    int j = r & 7;
    P[((ks * 8 + ct) * 64 + lane) * 8 + j] = __float2half_rn(W[k * NF + n]);
}

// bucket-binned scatter, fixed-capacity buckets (R8 geometry: 202 blocks, 84B runs)
__global__ __launch_bounds__(1024) void k_binscatter(const int* __restrict__ ei,
                                                     int* __restrict__ bcur,
                                                     int* __restrict__ packed) {
    __shared__ int h[NB], lcur[NB], garr[NB];
    int t = threadIdx.x;
    for (int i = t; i < NB; i += 1024) h[i] = 0;
    __syncthreads();
    int base = blockIdx.x * EPB;
    int pk[EPB / 1024];
    int bk[EPB / 1024];
#pragma unroll
    for (int k = 0; k < EPB / 1024; ++k) {
        int i = base + k * 1024 + t;
        if (i < ET) {
            int s, d;
            if (i < E) { s = ei[i]; d = ei[E + i]; } else { s = i - E; d = i - E; }
            bk[k] = d >> 7;
            pk[k] = s | ((d & (BSH - 1)) << 16);
            atomicAdd(&h[bk[k]], 1);
        } else bk[k] = -1;
    }
    __syncthreads();
    for (int i = t; i < NB; i += 1024) {
        lcur[i] = 0;
        garr[i] = h[i] ? atomicAdd(&bcur[i], h[i]) : 0;
    }
    __syncthreads();
#pragma unroll
    for (int k = 0; k < EPB / 1024; ++k) {
        if (bk[k] >= 0) {
            int p = garr[bk[k]] + atomicAdd(&lcur[bk[k]], 1);
            packed[p] = pk[k];
        }
    }
}

// one block per bucket: counting sort over 128 dsts in LDS.
// 128-bin scan by a single wave, 2 bins per lane (6 shfl rounds, 2 barriers).
__global__ __launch_bounds__(512) void k_csr(const int* __restrict__ packed,
                                             const int* __restrict__ bcur,
                                             int* __restrict__ offB, int* __restrict__ offE,
                                             unsigned short* __restrict__ srcs) {
    int b = blockIdx.x;
    int t = threadIdx.x;
    int s0 = b * CAP;
    int n = bcur[b] - s0;
    __shared__ int buf[CAP];
    __shared__ int h[BSH], bas[BSH], lcur[BSH];
    for (int i = t; i < n; i += 512) buf[i] = packed[s0 + i];
    if (t < BSH) { h[t] = 0; lcur[t] = 0; }
    __syncthreads();
    for (int i = t; i < n; i += 512)
        atomicAdd(&h[(buf[i] >> 16) & (BSH - 1)], 1);
    __syncthreads();
    if (t < 64) {                           // one wave scans 128 bins, 2 per lane
        int v0 = h[2 * t], v1 = h[2 * t + 1];
        int pair = v0 + v1, x = pair;
#pragma unroll
        for (int o = 1; o < 64; o <<= 1) {
            int y = __shfl_up(x, o);
            if (t >= o) x += y;
        }
        int e0 = s0 + x - pair;             // exclusive base of bin 2t
        int e1 = e0 + v0;                   // exclusive base of bin 2t+1
        bas[2 * t] = e0; bas[2 * t + 1] = e1;
        int d = b * BSH + 2 * t;
        if (d < N)     { offB[d] = e0;     offE[d] = e1; }
        if (d + 1 < N) { offB[d + 1] = e1; offE[d + 1] = s0 + x; }
    }
    __syncthreads();
    for (int i = t; i < n; i += 512) {
        int p = buf[i];
        int dl = (p >> 16) & (BSH - 1);
        int pos = bas[dl] + atomicAdd(&lcur[dl], 1);
        srcs[pos] = (unsigned short)(p & 0xFFFF);
    }
}

// H16 = fp16(A @ W) via mfma_f32_16x16x32_f16; A fp32 (layer1) or fp16 (layer2).
// Alpha projections fused from fp32 accumulators.
template <typename AT>
__global__ __launch_bounds__(256) void k_gemm_mfma(
    const AT* __restrict__ A, const __half* __restrict__ Wpk,
    const float* __restrict__ asv, const float* __restrict__ adv,
    __half* __restrict__ H16, float* __restrict__ AS, float* __restrict__ AD) {
    int t = threadIdx.x;
    int wave = t >> 6, lane = t & 63;
    int base = blockIdx.x * 64 + wave * 16;

    int row_a = base + (lane & 15);
    if (row_a >= N) row_a = N - 1;
    const AT* Arow = A + (size_t)row_a * NF;
    const half8* BP = (const half8*)Wpk;

    f32x4 acc[8] = {};
#pragma unroll
    for (int ks = 0; ks < 4; ++ks) {
        int eo = (ks * 4 + (lane >> 4)) * 8;
        half8 a;
        if constexpr (sizeof(AT) == 4) {
            float4 u = *(const float4*)(Arow + eo);
            float4 v = *(const float4*)(Arow + eo + 4);
            a[0] = (_Float16)u.x; a[1] = (_Float16)u.y; a[2] = (_Float16)u.z; a[3] = (_Float16)u.w;
            a[4] = (_Float16)v.x; a[5] = (_Float16)v.y; a[6] = (_Float16)v.z; a[7] = (_Float16)v.w;
        } else {
            a = ((const half8*)Arow)[ks * 4 + (lane >> 4)];
        }
#pragma unroll
        for (int ct = 0; ct < 8; ++ct) {
            half8 b = BP[(ks * 8 + ct) * 64 + lane];
            acc[ct] = __builtin_amdgcn_mfma_f32_16x16x32_f16(a, b, acc[ct], 0, 0, 0);
        }
    }

    int colb = lane & 15;
    int rowq = base + (lane >> 4) * 4;
    float ps[4] = {0.f, 0.f, 0.f, 0.f};
    float pd[4] = {0.f, 0.f, 0.f, 0.f};
#pragma unroll
    for (int ct = 0; ct < 8; ++ct) {
        int col = ct * 16 + colb;
        float av = asv[col], dv = adv[col];
#pragma unroll
        for (int r = 0; r < 4; ++r) {
            float h = acc[ct][r];
            if (rowq + r < N) H16[(size_t)(rowq + r) * NF + col] = __float2half_rn(h);
            ps[r] = fmaf(h, av, ps[r]);
            pd[r] = fmaf(h, dv, pd[r]);
        }
    }
#pragma unroll
    for (int r = 0; r < 4; ++r) {
#pragma unroll
        for (int o = 1; o <= 8; o <<= 1) {
            ps[r] += __shfl_xor(ps[r], o);
            pd[r] += __shfl_xor(pd[r], o);
        }
    }
    if (colb == 0) {
#pragma unroll
        for (int r = 0; r < 4; ++r) {
            if (rowq + r < N) { AS[rowq + r] = ps[r]; AD[rowq + r] = pd[r]; }
        }
    }
}

// wave-per-dst softmax+aggregate; no max pass (exp clamp), no barriers.
template <typename OUTT, int ACT>
__global__ __launch_bounds__(256) void k_aggregate(
    const __half* __restrict__ H16, const float* __restrict__ AS, const float* __restrict__ AD,
    const int* __restrict__ offB, const int* __restrict__ offE,
    const unsigned short* __restrict__ srcs,
    const float* __restrict__ bias, OUTT* __restrict__ OUT) {
    int wave = threadIdx.x >> 6, lane = threadIdx.x & 63;
    int d = blockIdx.x * 4 + wave;

    __shared__ float ssv[4][SCAPW];
    __shared__ unsigned short ssrc[4][SCAPW];

    int beg = offB[d], deg = offE[d] - beg;
    float ad = AD[d];

    // pass 1: one exp per edge, stash (e, src), wave-reduce denominator
    float ls = 0.f;
    for (int i = lane; i < deg; i += 64) {
        int s = srcs[beg + i];
        float sv = AS[s] + ad;
        sv = (sv > 0.f) ? sv : 0.2f * sv;
        float e = __expf(fminf(sv, 60.f));
        if (i < SCAPW) { ssv[wave][i] = e; ssrc[wave][i] = (unsigned short)s; }
        ls += e;
    }
#pragma unroll
    for (int o = 1; o <= 32; o <<= 1) ls += __shfl_xor(ls, o);
    float inv = 1.f / (ls + 1e-16f);

    // pass 2: gather-accumulate, 2x unrolled (8 edges in flight per wave)
    int tx = lane & 15, u = lane >> 4;
    float acc[8] = {0.f, 0.f, 0.f, 0.f, 0.f, 0.f, 0.f, 0.f};
    for (int j0 = 0; j0 < deg; j0 += 8) {
        int i0 = j0 + u, i1 = j0 + 4 + u;
        float e0 = 0.f, e1 = 0.f;
        int s0 = 0, s1 = 0;
        bool v0 = i0 < deg, v1 = i1 < deg;
        if (v0) {
            if (i0 < SCAPW) { e0 = ssv[wave][i0]; s0 = ssrc[wave][i0]; }
            else {
                s0 = srcs[beg + i0];
                float sv = AS[s0] + ad;
                sv = (sv > 0.f) ? sv : 0.2f * sv;
                e0 = __expf(fminf(sv, 60.f));
            }
        }
        if (v1) {
            if (i1 < SCAPW) { e1 = ssv[wave][i1]; s1 = ssrc[wave][i1]; }
            else {
                s1 = srcs[beg + i1];
                float sv = AS[s1] + ad;
                sv = (sv > 0.f) ? sv : 0.2f * sv;
                e1 = __expf(fminf(sv, 60.f));
            }
        }
        union { float4 f; __half2 h[4]; } va, vb;
        if (v0) va.f = *reinterpret_cast<const float4*>(H16 + (size_t)s0 * NF + tx * 8);
        if (v1) vb.f = *reinterpret_cast<const float4*>(H16 + (size_t)s1 * NF + tx * 8);
        if (v0) {
            float2 f0 = __half22float2(va.h[0]);
            float2 f1 = __half22float2(va.h[1]);
            float2 f2 = __half22float2(va.h[2]);
            float2 f3 = __half22float2(va.h[3]);
            acc[0] = fmaf(e0, f0.x, acc[0]); acc[1] = fmaf(e0, f0.y, acc[1]);
            acc[2] = fmaf(e0, f1.x, acc[2]); acc[3] = fmaf(e0, f1.y, acc[3]);
            acc[4] = fmaf(e0, f2.x, acc[4]); acc[5] = fmaf(e0, f2.y, acc[5]);
            acc[6] = fmaf(e0, f3.x, acc[6]); acc[7] = fmaf(e0, f3.y, acc[7]);
        }
        if (v1) {
            float2 f0 = __half22float2(vb.h[0]);
            float2 f1 = __half22float2(vb.h[1]);
            float2 f2 = __half22float2(vb.h[2]);
            float2 f3 = __half22float2(vb.h[3]);
            acc[0] = fmaf(e1, f0.x, acc[0]); acc[1] = fmaf(e1, f0.y, acc[1]);
            acc[2] = fmaf(e1, f1.x, acc[2]); acc[3] = fmaf(e1, f1.y, acc[3]);
            acc[4] = fmaf(e1, f2.x, acc[4]); acc[5] = fmaf(e1, f2.y, acc[5]);
            acc[6] = fmaf(e1, f3.x, acc[6]); acc[7] = fmaf(e1, f3.y, acc[7]);
        }
    }
#pragma unroll
    for (int o = 16; o <= 32; o <<= 1) {
#pragma unroll
        for (int i = 0; i < 8; ++i) acc[i] += __shfl_xor(acc[i], o);
    }
    if (lane < 16) {
        float o8[8];
#pragma unroll
        for (int i = 0; i < 8; ++i) {
            float v = acc[i] * inv + bias[tx * 8 + i];
            o8[i] = (ACT && v < 0.f) ? 0.01f * v : v;
        }
        if constexpr (sizeof(OUTT) == 2) {
            union { __half2 h[4]; float4 f; } pk;
            pk.h[0] = __floats2half2_rn(o8[0], o8[1]);
            pk.h[1] = __floats2half2_rn(o8[2], o8[3]);
            pk.h[2] = __floats2half2_rn(o8[4], o8[5]);
            pk.h[3] = __floats2half2_rn(o8[6], o8[7]);
            ((float4*)OUT)[(size_t)d * 16 + tx] = pk.f;
        } else {
            float4 w0 = {o8[0], o8[1], o8[2], o8[3]};
            float4 w1 = {o8[4], o8[5], o8[6], o8[7]};
            ((float4*)OUT)[(size_t)d * 32 + tx * 2]     = w0;
            ((float4*)OUT)[(size_t)d * 32 + tx * 2 + 1] = w1;
        }
    }
}

extern "C" void kernel_launch(void* const* d_in, const int* in_sizes, int n_in,
                              void* d_out, int out_size, void* d_ws, size_t ws_size,
                              hipStream_t stream) {
    const float* x   = (const float*)d_in[0];
    const int*   ei  = (const int*)d_in[1];
    const float* W1  = (const float*)d_in[2];
    const float* as1 = (const float*)d_in[3];
    const float* ad1 = (const float*)d_in[4];
    const float* b1  = (const float*)d_in[5];
    const float* W2  = (const float*)d_in[6];
    const float* as2 = (const float*)d_in[7];
    const float* ad2 = (const float*)d_in[8];
    const float* b2  = (const float*)d_in[9];
    float* out = (float*)d_out;

    char* p = (char*)d_ws;
    auto alloc = [&](size_t bytes) { char* r = p; p += (bytes + 255) & ~size_t(255); return (void*)r; };
    int* bcur  = (int*)alloc(sizeof(int) * NB);
    int* offB  = (int*)alloc(sizeof(int) * N);
    int* offE  = (int*)alloc(sizeof(int) * N);
    unsigned short* srcs = (unsigned short*)alloc(sizeof(unsigned short) * (size_t)NB * CAP);
    __half* H16   = (__half*)alloc(sizeof(__half) * (size_t)N * NF);
    __half* HMID16= (__half*)alloc(sizeof(__half) * (size_t)N * NF);
    __half* Wpk1  = (__half*)alloc(sizeof(__half) * NF * NF);
    __half* Wpk2  = (__half*)alloc(sizeof(__half) * NF * NF);
    float* AS  = (float*)alloc(sizeof(float) * N);
    float* AD  = (float*)alloc(sizeof(float) * N);
    int* packed = (int*)alloc(sizeof(int) * (size_t)NB * CAP);

    // fused init (bucket cursors + weight packing)
    k_init_packw<<<(2 * NF * NF + 255) / 256, 256, 0, stream>>>(bcur, W1, W2, Wpk1, Wpk2);
    // CSR build: fixed-capacity bucket binning (no hist pass, no global scan)
    k_binscatter<<<NBLK, 1024, 0, stream>>>(ei, bcur, packed);
    k_csr<<<NB, 512, 0, stream>>>(packed, bcur, offB, offE, srcs);

    // layer 1 (A = fp32 x, converted in-register)
    k_gemm_mfma<float><<<(N + 63) / 64, 256, 0, stream>>>(x, Wpk1, as1, ad1, H16, AS, AD);
    k_aggregate<__half, 1><<<N / 4, 256, 0, stream>>>(H16, AS, AD, offB, offE, srcs, b1, HMID16);
    // layer 2 (A = fp16 HMID16)
    k_gemm_mfma<__half><<<(N + 63) / 64, 256, 0, stream>>>(HMID16, Wpk2, as2, ad2, H16, AS, AD);
    k_aggregate<float, 0><<<N / 4, 256, 0, stream>>>(H16, AS, AD, offB, offE, srcs, b2, out);
}

// Round 11
// 178.222 us; speedup vs baseline: 1.2220x; 1.0028x over previous
//
#include <hip/hip_runtime.h>
#include <hip/hip_fp16.h>

constexpr int N  = 50000;
constexpr int E  = 1600000;
constexpr int ET = E + N;                   // with self-loops
constexpr int NF = 128;
constexpr int BSH = 128;                    // dsts per bucket
constexpr int NB = (N + BSH - 1) / BSH;     // 391 buckets
constexpr int CAP = 8192;                   // slots per bucket (mean 4224, sigma 65)
constexpr int EPB  = 8192;                  // edges per block (binscatter)
constexpr int NBLK = (ET + EPB - 1) / EPB;  // 202
constexpr int PACKW_BLKS = (2 * NF * NF + 1023) / 1024;  // 32
constexpr int GEMM1_BLKS = (N + 127) / 128; // 391 (128 rows per 512-thread block)
constexpr int SCAPW = 128;                  // per-wave edge stash in aggregate

typedef _Float16 half8 __attribute__((ext_vector_type(8)));
typedef float    f32x4 __attribute__((ext_vector_type(4)));

// ---------------- fused binscatter + weight packing ----------------
// blocks [0,NBLK): bucket-binned scatter (bcur holds OFFSETS, memset-0 init)
// blocks [NBLK, NBLK+PACKW_BLKS): pack W1,W2 into MFMA B-fragment order fp16
__global__ __launch_bounds__(1024) void k_scatter_packw(
    const int* __restrict__ ei, int* __restrict__ bcur, int* __restrict__ packed,
    const float* __restrict__ W1, const float* __restrict__ W2,
    __half* __restrict__ P1, __half* __restrict__ P2) {
    int t = threadIdx.x;
    if (blockIdx.x >= NBLK) {               // ---- packw path ----
        int tid = (blockIdx.x - NBLK) * 1024 + t;
        if (tid >= 2 * NF * NF) return;
        int which = tid >> 14;
        int id = tid & (NF * NF - 1);
        int k = id >> 7, n = id & 127;
        const float* W = which ? W2 : W1;
        __half* P = which ? P2 : P1;
        int ks = k >> 5, r = k & 31, ct = n >> 4;
        int lane = ((r >> 3) << 4) | (n & 15);
        int j = r & 7;
        P[((ks * 8 + ct) * 64 + lane) * 8 + j] = __float2half_rn(W[k * NF + n]);
        return;
    }
    // ---- binscatter path ----
    __shared__ int h[NB], lcur[NB], garr[NB];
    for (int i = t; i < NB; i += 1024) h[i] = 0;
    __syncthreads();
    int base = blockIdx.x * EPB;
    int pk[EPB / 1024];
    int bk[EPB / 1024];
#pragma unroll
    for (int k = 0; k < EPB / 1024; ++k) {
        int i = base + k * 1024 + t;
        if (i < ET) {
            int s, d;
            if (i < E) { s = ei[i]; d = ei[E + i]; } else { s = i - E; d = i - E; }
            bk[k] = d >> 7;
            pk[k] = s | ((d & (BSH - 1)) << 16);
            atomicAdd(&h[bk[k]], 1);
        } else bk[k] = -1;
    }
    __syncthreads();
    for (int i = t; i < NB; i += 1024) {
        lcur[i] = 0;
        garr[i] = i * CAP + (h[i] ? atomicAdd(&bcur[i], h[i]) : 0);
    }
    __syncthreads();
#pragma unroll
    for (int k = 0; k < EPB / 1024; ++k) {
        if (bk[k] >= 0) {
            int p = garr[bk[k]] + atomicAdd(&lcur[bk[k]], 1);
            packed[p] = pk[k];
        }
    }
}

// ---------------- shared GEMM wave body (16 rows x 128 cols) ----------------
template <typename AT>
__device__ __forceinline__ void gemm_rows16(
    const AT* __restrict__ A, const half8* __restrict__ BP,
    const float* __restrict__ asv, const float* __restrict__ adv,
    __half* __restrict__ H16, float* __restrict__ AS, float* __restrict__ AD,
    int base, int lane) {
    int row_a = base + (lane & 15);
    if (row_a >= N) row_a = N - 1;
    const AT* Arow = A + (size_t)row_a * NF;

    f32x4 acc[8] = {};
#pragma unroll
    for (int ks = 0; ks < 4; ++ks) {
        int eo = (ks * 4 + (lane >> 4)) * 8;
        half8 a;
        if constexpr (sizeof(AT) == 4) {
            float4 u = *(const float4*)(Arow + eo);
            float4 v = *(const float4*)(Arow + eo + 4);
            a[0] = (_Float16)u.x; a[1] = (_Float16)u.y; a[2] = (_Float16)u.z; a[3] = (_Float16)u.w;
            a[4] = (_Float16)v.x; a[5] = (_Float16)v.y; a[6] = (_Float16)v.z; a[7] = (_Float16)v.w;
        } else {
            a = ((const half8*)Arow)[ks * 4 + (lane >> 4)];
        }
#pragma unroll
        for (int ct = 0; ct < 8; ++ct) {
            half8 b = BP[(ks * 8 + ct) * 64 + lane];
            acc[ct] = __builtin_amdgcn_mfma_f32_16x16x32_f16(a, b, acc[ct], 0, 0, 0);
        }
    }

    int colb = lane & 15;
    int rowq = base + (lane >> 4) * 4;
    float ps[4] = {0.f, 0.f, 0.f, 0.f};
    float pd[4] = {0.f, 0.f, 0.f, 0.f};
#pragma unroll
    for (int ct = 0; ct < 8; ++ct) {
        int col = ct * 16 + colb;
        float av = asv[col], dv = adv[col];
#pragma unroll
        for (int r = 0; r < 4; ++r) {
            float hv = acc[ct][r];
            if (rowq + r < N) H16[(size_t)(rowq + r) * NF + col] = __float2half_rn(hv);
            ps[r] = fmaf(hv, av, ps[r]);
            pd[r] = fmaf(hv, dv, pd[r]);
        }
    }
#pragma unroll
    for (int r = 0; r < 4; ++r) {
#pragma unroll
        for (int o = 1; o <= 8; o <<= 1) {
            ps[r] += __shfl_xor(ps[r], o);
            pd[r] += __shfl_xor(pd[r], o);
        }
    }
    if (colb == 0) {
#pragma unroll
        for (int r = 0; r < 4; ++r) {
            if (rowq + r < N) { AS[rowq + r] = ps[r]; AD[rowq + r] = pd[r]; }
        }
    }
}

// ---------------- fused k_csr + layer-1 GEMM ----------------
// even blocks: GEMM1 stripe (128 rows, 8 waves); odd blocks: bucket counting sort
__global__ __launch_bounds__(512) void k_csr_gemm1(
    const int* __restrict__ packed, const int* __restrict__ bcur,
    int* __restrict__ offB, int* __restrict__ offE, unsigned short* __restrict__ srcs,
    const float* __restrict__ X, const __half* __restrict__ Wpk,
    const float* __restrict__ asv, const float* __restrict__ adv,
    __half* __restrict__ H16, float* __restrict__ AS, float* __restrict__ AD) {
    int t = threadIdx.x;
    if ((blockIdx.x & 1) == 0) {            // ---- GEMM1 path ----
        int blk = blockIdx.x >> 1;
        int wave = t >> 6, lane = t & 63;
        int base = blk * 128 + wave * 16;
        gemm_rows16<float>(X, (const half8*)Wpk, asv, adv, H16, AS, AD, base, lane);
        return;
    }
    // ---- csr path ----
    int b = blockIdx.x >> 1;
    int s0 = b * CAP;
    int n = bcur[b];
    __shared__ int buf[CAP];
    __shared__ int h[BSH], bas[BSH], lcur[BSH];
    for (int i = t; i < n; i += 512) buf[i] = packed[s0 + i];
    if (t < BSH) { h[t] = 0; lcur[t] = 0; }
    __syncthreads();
    for (int i = t; i < n; i += 512)
        atomicAdd(&h[(buf[i] >> 16) & (BSH - 1)], 1);
    __syncthreads();
    if (t < 64) {                           // one wave scans 128 bins, 2 per lane
        int v0 = h[2 * t], v1 = h[2 * t + 1];
        int pair = v0 + v1, x = pair;
#pragma unroll
        for (int o = 1; o < 64; o <<= 1) {
            int y = __shfl_up(x, o);
            if (t >= o) x += y;
        }
        int e0 = s0 + x - pair;
        int e1 = e0 + v0;
        bas[2 * t] = e0; bas[2 * t + 1] = e1;
        int d = b * BSH + 2 * t;
        if (d < N)     { offB[d] = e0;     offE[d] = e1; }
        if (d + 1 < N) { offB[d + 1] = e1; offE[d + 1] = s0 + x; }
    }
    __syncthreads();
    for (int i = t; i < n; i += 512) {
        int p = buf[i];
        int dl = (p >> 16) & (BSH - 1);
        int pos = bas[dl] + atomicAdd(&lcur[dl], 1);
        srcs[pos] = (unsigned short)(p & 0xFFFF);
    }
}

// ---------------- standalone layer-2 GEMM (256 threads, 64 rows) ----------------
__global__ __launch_bounds__(256) void k_gemm_mfma2(
    const __half* __restrict__ A, const __half* __restrict__ Wpk,
    const float* __restrict__ asv, const float* __restrict__ adv,
    __half* __restrict__ H16, float* __restrict__ AS, float* __restrict__ AD) {
    int t = threadIdx.x;
    int wave = t >> 6, lane = t & 63;
    int base = blockIdx.x * 64 + wave * 16;
    gemm_rows16<__half>(A, (const half8*)Wpk, asv, adv, H16, AS, AD, base, lane);
}

// ---------------- wave-per-dst softmax + aggregate (unchanged, at floor) ----------------
template <typename OUTT, int ACT>
__global__ __launch_bounds__(256) void k_aggregate(
    const __half* __restrict__ H16, const float* __restrict__ AS, const float* __restrict__ AD,
    const int* __restrict__ offB, const int* __restrict__ offE,
    const unsigned short* __restrict__ srcs,
    const float* __restrict__ bias, OUTT* __restrict__ OUT) {
    int wave = threadIdx.x >> 6, lane = threadIdx.x & 63;
    int d = blockIdx.x * 4 + wave;

    __shared__ float ssv[4][SCAPW];
    __shared__ unsigned short ssrc[4][SCAPW];

    int beg = offB[d], deg = offE[d] - beg;
    float ad = AD[d];

    float ls = 0.f;
    for (int i = lane; i < deg; i += 64) {
        int s = srcs[beg + i];
        float sv = AS[s] + ad;
        sv = (sv > 0.f) ? sv : 0.2f * sv;
        float e = __expf(fminf(sv, 60.f));
        if (i < SCAPW) { ssv[wave][i] = e; ssrc[wave][i] = (unsigned short)s; }
        ls += e;
    }
#pragma unroll
    for (int o = 1; o <= 32; o <<= 1) ls += __shfl_xor(ls, o);
    float inv = 1.f / (ls + 1e-16f);

    int tx = lane & 15, u = lane >> 4;
    float acc[8] = {0.f, 0.f, 0.f, 0.f, 0.f, 0.f, 0.f, 0.f};
    for (int j0 = 0; j0 < deg; j0 += 8) {
        int i0 = j0 + u, i1 = j0 + 4 + u;
        float e0 = 0.f, e1 = 0.f;
        int s0 = 0, s1 = 0;
        bool v0 = i0 < deg, v1 = i1 < deg;
        if (v0) {
            if (i0 < SCAPW) { e0 = ssv[wave][i0]; s0 = ssrc[wave][i0]; }
            else {
                s0 = srcs[beg + i0];
                float sv = AS[s0] + ad;
                sv = (sv > 0.f) ? sv : 0.2f * sv;
                e0 = __expf(fminf(sv, 60.f));
            }
        }
        if (v1) {
            if (i1 < SCAPW) { e1 = ssv[wave][i1]; s1 = ssrc[wave][i1]; }
            else {
                s1 = srcs[beg + i1];
                float sv = AS[s1] + ad;
                sv = (sv > 0.f) ? sv : 0.2f * sv;
                e1 = __expf(fminf(sv, 60.f));
            }
        }
        union { float4 f; __half2 h[4]; } va, vb;
        if (v0) va.f = *reinterpret_cast<const float4*>(H16 + (size_t)s0 * NF + tx * 8);
        if (v1) vb.f = *reinterpret_cast<const float4*>(H16 + (size_t)s1 * NF + tx * 8);
        if (v0) {
            float2 f0 = __half22float2(va.h[0]);
            float2 f1 = __half22float2(va.h[1]);
            float2 f2 = __half22float2(va.h[2]);
            float2 f3 = __half22float2(va.h[3]);
            acc[0] = fmaf(e0, f0.x, acc[0]); acc[1] = fmaf(e0, f0.y, acc[1]);
            acc[2] = fmaf(e0, f1.x, acc[2]); acc[3] = fmaf(e0, f1.y, acc[3]);
            acc[4] = fmaf(e0, f2.x, acc[4]); acc[5] = fmaf(e0, f2.y, acc[5]);
            acc[6] = fmaf(e0, f3.x, acc[6]); acc[7] = fmaf(e0, f3.y, acc[7]);
        }
        if (v1) {
            float2 f0 = __half22float2(vb.h[0]);
            float2 f1 = __half22float2(vb.h[1]);
            float2 f2 = __half22float2(vb.h[2]);
            float2 f3 = __half22float2(vb.h[3]);
            acc[0] = fmaf(e1, f0.x, acc[0]); acc[1] = fmaf(e1, f0.y, acc[1]);
            acc[2] = fmaf(e1, f1.x, acc[2]); acc[3] = fmaf(e1, f1.y, acc[3]);
            acc[4] = fmaf(e1, f2.x, acc[4]); acc[5] = fmaf(e1, f2.y, acc[5]);
            acc[6] = fmaf(e1, f3.x, acc[6]); acc[7] = fmaf(e1, f3.y, acc[7]);
        }
    }
#pragma unroll
    for (int o = 16; o <= 32; o <<= 1) {
#pragma unroll
        for (int i = 0; i < 8; ++i) acc[i] += __shfl_xor(acc[i], o);
    }
    if (lane < 16) {
        float o8[8];
#pragma unroll
        for (int i = 0; i < 8; ++i) {
            float v = acc[i] * inv + bias[tx * 8 + i];
            o8[i] = (ACT && v < 0.f) ? 0.01f * v : v;
        }
        if constexpr (sizeof(OUTT) == 2) {
            union { __half2 h[4]; float4 f; } pk;
            pk.h[0] = __floats2half2_rn(o8[0], o8[1]);
            pk.h[1] = __floats2half2_rn(o8[2], o8[3]);
            pk.h[2] = __floats2half2_rn(o8[4], o8[5]);
            pk.h[3] = __floats2half2_rn(o8[6], o8[7]);
            ((float4*)OUT)[(size_t)d * 16 + tx] = pk.f;
        } else {
            float4 w0 = {o8[0], o8[1], o8[2], o8[3]};
            float4 w1 = {o8[4], o8[5], o8[6], o8[7]};
            ((float4*)OUT)[(size_t)d * 32 + tx * 2]     = w0;
            ((float4*)OUT)[(size_t)d * 32 + tx * 2 + 1] = w1;
        }
    }
}

extern "C" void kernel_launch(void* const* d_in, const int* in_sizes, int n_in,
                              void* d_out, int out_size, void* d_ws, size_t ws_size,
                              hipStream_t stream) {
    const float* x   = (const float*)d_in[0];
    const int*   ei  = (const int*)d_in[1];
    const float* W1  = (const float*)d_in[2];
    const float* as1 = (const float*)d_in[3];
    const float* ad1 = (const float*)d_in[4];
    const float* b1  = (const float*)d_in[5];
    const float* W2  = (const float*)d_in[6];
    const float* as2 = (const float*)d_in[7];
    const float* ad2 = (const float*)d_in[8];
    const float* b2  = (const float*)d_in[9];
    float* out = (float*)d_out;

    char* p = (char*)d_ws;
    auto alloc = [&](size_t bytes) { char* r = p; p += (bytes + 255) & ~size_t(255); return (void*)r; };
    int* bcur  = (int*)alloc(sizeof(int) * NB);
    int* offB  = (int*)alloc(sizeof(int) * N);
    int* offE  = (int*)alloc(sizeof(int) * N);
    unsigned short* srcs = (unsigned short*)alloc(sizeof(unsigned short) * (size_t)NB * CAP);
    __half* H16   = (__half*)alloc(sizeof(__half) * (size_t)N * NF);
    __half* HMID16= (__half*)alloc(sizeof(__half) * (size_t)N * NF);
    __half* Wpk1  = (__half*)alloc(sizeof(__half) * NF * NF);
    __half* Wpk2  = (__half*)alloc(sizeof(__half) * NF * NF);
    float* AS  = (float*)alloc(sizeof(float) * N);
    float* AD  = (float*)alloc(sizeof(float) * N);
    int* packed = (int*)alloc(sizeof(int) * (size_t)NB * CAP);

    // cursors are offsets from i*CAP -> plain memset
    hipMemsetAsync(bcur, 0, sizeof(int) * NB, stream);
    // binscatter + weight packing in one dispatch
    k_scatter_packw<<<NBLK + PACKW_BLKS, 1024, 0, stream>>>(ei, bcur, packed, W1, W2, Wpk1, Wpk2);
    // bucket counting-sort + layer-1 GEMM co-scheduled in one dispatch
    k_csr_gemm1<<<2 * GEMM1_BLKS, 512, 0, stream>>>(packed, bcur, offB, offE, srcs,
                                                    x, Wpk1, as1, ad1, H16, AS, AD);
    // layer 1 aggregate
    k_aggregate<__half, 1><<<N / 4, 256, 0, stream>>>(H16, AS, AD, offB, offE, srcs, b1, HMID16);
    // layer 2
    k_gemm_mfma2<<<(N + 63) / 64, 256, 0, stream>>>(HMID16, Wpk2, as2, ad2, H16, AS, AD);
    k_aggregate<float, 0><<<N / 4, 256, 0, stream>>>(H16, AS, AD, offB, offE, srcs, b2, out);
}